// Round 3
// baseline (215.840 us; speedup 1.0000x reference)
//
#include <hip/hip_runtime.h>

#define BINS 10
#define ALPHA 0.75f

constexpr int NB    = 2048;   // pass-1 blocks
constexpr int NT    = 256;    // pass-1 threads per block (4 waves)
constexpr int ITERS = 8;      // float4 iterations per thread on the fast path
constexpr int NT2   = 1024;   // pass-2 threads (single block, 16 waves)

// Cumulative bin thresholds on u = diff*(2t-1):
//   g = sigmoid(-diff*(2t-1)) = 1/(1+e^u)  (monotone decreasing in u)
//   g >= k/10  <=>  u <= L_k,  L_k = ln((10-k)/k)
// bin(g) = #{k in 1..9 : u <= L_k}; per-bin values recovered in pass 2 by
// differencing the cumulative sums. No exp/rcp needed in the hot loop.
__device__ __constant__ float LTH[9] = {
    2.19722458f,  1.38629436f,  0.847297861f, 0.405465108f, 0.0f,
   -0.405465108f, -0.847297861f, -1.38629436f, -2.19722458f};

// Per-element update: cls[0] += loss (all elems); for k=1..9:
//   p = (u <= L_k);  cls[k] += p ? loss : 0;  cnt[k] += p.
// loss = max(0, -t*diff) is nonzero only for t==1 (t in {0,1}).
#define GHM_PROC(AX, BX, TX) do {                                    \
    float diff = (AX) - (BX);                                        \
    float nd   = -diff;                                              \
    bool  tt   = (TX) != 0;                                          \
    float u    = tt ? diff : nd;                                     \
    float loss = tt ? fmaxf(nd, 0.0f) : 0.0f;                        \
    cls[0] += loss;                                                  \
    _Pragma("unroll")                                                \
    for (int k = 1; k < BINS; ++k) {                                 \
      bool p = (u <= LTH[k - 1]);                                    \
      cls[k] += p ? loss : 0.0f;                                     \
      cnt[k] += (unsigned int)p;                                     \
    }                                                                \
  } while (0)

// Pass 1: fused elementwise + cumulative per-bin {count, loss-sum}.
// Fast path (n == NB*NT*ITERS*4): fixed trip count, all 24 vector loads
// issued into registers up front so the memory pipe has deep MLP.
// __launch_bounds__(NT,4): cap VGPR at 128 (16 waves/CU) — trade occupancy
// for in-flight loads (latency-bound regime, G7).
__global__ __launch_bounds__(NT, 4) void ghm_pass1(
    const float* __restrict__ o1f, const float* __restrict__ o2f,
    const int* __restrict__ tgt, float* __restrict__ lsum_part,
    unsigned int* __restrict__ cnt_part, int n)
{
  const float4* o1 = reinterpret_cast<const float4*>(o1f);
  const float4* o2 = reinterpret_cast<const float4*>(o2f);
  const int4*   tg = reinterpret_cast<const int4*>(tgt);

  float        cls[BINS];   // cls[0] = total loss; cls[k] cumulative
  unsigned int cnt[BINS];   // cnt[k], k>=1 cumulative counts; cnt[0] stays 0
#pragma unroll
  for (int b = 0; b < BINS; ++b) { cls[b] = 0.0f; cnt[b] = 0u; }

  if (n == NB * NT * ITERS * 4 && gridDim.x == NB) {
    // Block-contiguous chunk: block owns NT*ITERS consecutive float4s.
    const int base = blockIdx.x * (NT * ITERS) + threadIdx.x;
    float4 av[ITERS], bv[ITERS];
    int4   tv[ITERS];
#pragma unroll
    for (int k = 0; k < ITERS; ++k) {
      av[k] = o1[base + k * NT];
      bv[k] = o2[base + k * NT];
      tv[k] = tg[base + k * NT];
    }
#pragma unroll
    for (int k = 0; k < ITERS; ++k) {
      GHM_PROC(av[k].x, bv[k].x, tv[k].x);
      GHM_PROC(av[k].y, bv[k].y, tv[k].y);
      GHM_PROC(av[k].z, bv[k].z, tv[k].z);
      GHM_PROC(av[k].w, bv[k].w, tv[k].w);
    }
  } else {
    // Generic grid-stride fallback (any n, any grid).
    const int tid = blockIdx.x * NT + threadIdx.x;
    const int stride = gridDim.x * NT;
    const int n4 = n >> 2;
    for (int i = tid; i < n4; i += stride) {
      float4 a  = o1[i];
      float4 bb = o2[i];
      int4   t  = tg[i];
      GHM_PROC(a.x, bb.x, t.x);
      GHM_PROC(a.y, bb.y, t.y);
      GHM_PROC(a.z, bb.z, t.z);
      GHM_PROC(a.w, bb.w, t.w);
    }
    if (tid == 0) {
      for (int i = n4 * 4; i < n; ++i) GHM_PROC(o1f[i], o2f[i], tgt[i]);
    }
  }

  // wave64 shuffle reduce, then cross-wave via LDS; one deterministic
  // partial per block (no atomics).
  const int lane = threadIdx.x & 63;
  const int wv   = threadIdx.x >> 6;
  __shared__ float        s_ls[NT / 64][BINS];
  __shared__ unsigned int s_c [NT / 64][BINS];
#pragma unroll
  for (int b = 0; b < BINS; ++b) {
    float v = cls[b];
    unsigned int cv = cnt[b];
#pragma unroll
    for (int off = 32; off >= 1; off >>= 1) {
      v  += __shfl_down(v, off, 64);
      cv += __shfl_down(cv, off, 64);
    }
    if (lane == 0) { s_ls[wv][b] = v; s_c[wv][b] = cv; }
  }
  __syncthreads();
  if (threadIdx.x < BINS) {
    float v = 0.0f; unsigned int cv = 0u;
#pragma unroll
    for (int w = 0; w < NT / 64; ++w) { v += s_ls[w][threadIdx.x]; cv += s_c[w][threadIdx.x]; }
    lsum_part[blockIdx.x * BINS + threadIdx.x] = v;
    cnt_part [blockIdx.x * BINS + threadIdx.x] = cv;
  }
}

// Pass 2: one wide block (16 waves) reduces per-block cumulative partials in
// double, differences cumulative->per-bin, applies w[b] = max((f32)cnt,1)^-0.75,
// writes the scalar mean.
__global__ __launch_bounds__(NT2) void ghm_pass2(
    const float* __restrict__ lsum_part, const unsigned int* __restrict__ cnt_part,
    float* __restrict__ out, int nparts, int n)
{
  double             cls[BINS];
  unsigned long long cc [BINS];
#pragma unroll
  for (int b = 0; b < BINS; ++b) { cls[b] = 0.0; cc[b] = 0ull; }

  for (int i = threadIdx.x; i < nparts; i += NT2) {
#pragma unroll
    for (int b = 0; b < BINS; ++b) {
      cls[b] += (double)lsum_part[i * BINS + b];
      cc[b]  += (unsigned long long)cnt_part[i * BINS + b];
    }
  }

  const int lane = threadIdx.x & 63;
  const int wv   = threadIdx.x >> 6;
  __shared__ double             s_ls[NT2 / 64][BINS];
  __shared__ unsigned long long s_c [NT2 / 64][BINS];
#pragma unroll
  for (int b = 0; b < BINS; ++b) {
    double v = cls[b];
    unsigned long long cv = cc[b];
#pragma unroll
    for (int off = 32; off >= 1; off >>= 1) {
      v  += __shfl_down(v, off, 64);
      cv += __shfl_down(cv, off, 64);
    }
    if (lane == 0) { s_ls[wv][b] = v; s_c[wv][b] = cv; }
  }
  __syncthreads();
  if (threadIdx.x == 0) {
    double             CLS[BINS + 1];
    unsigned long long CC [BINS + 1];
#pragma unroll
    for (int b = 0; b < BINS; ++b) {
      double lv = 0.0; unsigned long long cv = 0ull;
#pragma unroll
      for (int w = 0; w < NT2 / 64; ++w) { lv += s_ls[w][b]; cv += s_c[w][b]; }
      CLS[b] = lv; CC[b] = cv;
    }
    CLS[BINS] = 0.0; CC[BINS] = 0ull;
    CC[0] = (unsigned long long)n;  // cumulative count at k=0 is all elements

    double total = 0.0;
#pragma unroll
    for (int b = 0; b < BINS; ++b) {
      double lsb             = CLS[b] - CLS[b + 1];
      unsigned long long cb  = CC[b] - CC[b + 1];
      float cf  = (float)cb;           // counts.astype(float32)
      float tot = fmaxf(cf, 1.0f);     // clip(counts, 1.0)
      float wgt = powf(tot, -ALPHA);   // tot ** -0.75
      total += lsb * (double)wgt;
    }
    out[0] = (float)(total / (double)n);
  }
}

extern "C" void kernel_launch(void* const* d_in, const int* in_sizes, int n_in,
                              void* d_out, int out_size, void* d_ws, size_t ws_size,
                              hipStream_t stream) {
  const float* o1  = (const float*)d_in[0];
  const float* o2  = (const float*)d_in[1];
  const int*   tgt = (const int*)d_in[2];
  float* out = (float*)d_out;
  const int n = in_sizes[0];

  // ws layout: [nb][BINS] f32 cumulative loss partials, then [nb][BINS] u32
  // cumulative count partials. Every slot written by pass1 (no zero-init need).
  int nb = NB;
  size_t need = (size_t)nb * BINS * (sizeof(float) + sizeof(unsigned int));
  while (nb > 1 && need > ws_size) { nb >>= 1; need >>= 1; }  // safety only
  float* lsum_part = (float*)d_ws;
  unsigned int* cnt_part = (unsigned int*)((char*)d_ws + (size_t)nb * BINS * sizeof(float));

  ghm_pass1<<<nb, NT, 0, stream>>>(o1, o2, tgt, lsum_part, cnt_part, n);
  ghm_pass2<<<1, NT2, 0, stream>>>(lsum_part, cnt_part, out, nb, n);
}